// Round 1
// baseline (112.689 us; speedup 1.0000x reference)
//
#include <hip/hip_runtime.h>

// NCA step collapsed: y = (w1*w0) applied to depthwise-perception == single
// 8->8 channel 3x3 circular conv with folded kernel K[c][c'][3][3].
// out = clamp(grid + (noise<0.5) * conv(grid, K), 0, 1)

#define B_ 16
#define C_ 8
#define H_ 512
#define W_ 512
#define HID_ 32
#define F_ 5

#define TH 16
#define TW 64

// ---- prep: fold w1 @ w0 @ filters into K[8][8][9] ----
__global__ void nca_prep(const float* __restrict__ filters,  // [5][3][3]
                         const float* __restrict__ w0,       // [32][40]
                         const float* __restrict__ w1,       // [8][32]
                         float* __restrict__ K)               // [8][8][9]
{
    int idx = blockIdx.x * blockDim.x + threadIdx.x;
    if (idx >= C_ * C_ * 9) return;
    int k  = idx % 9;
    int t  = idx / 9;
    int cp = t % C_;   // input channel
    int c  = t / C_;   // output channel
    float acc = 0.f;
    #pragma unroll
    for (int f = 0; f < F_; ++f) {
        float we = 0.f;
        for (int o = 0; o < HID_; ++o)
            we += w1[c * HID_ + o] * w0[o * (C_ * F_) + cp * F_ + f];
        acc += we * filters[f * 9 + k];
    }
    K[idx] = acc;
}

// ---- main: tiled fused conv + mask + residual + clamp ----
__global__ __launch_bounds__(256) void nca_main(
    const float* __restrict__ grid,
    const float* __restrict__ noise,
    const float* __restrict__ K,      // [8][8][9]
    float* __restrict__ out)
{
    __shared__ float lds[C_][TH + 2][TW + 2];   // 8*18*66*4 = 38016 B

    const int b  = blockIdx.z;
    const int h0 = blockIdx.y * TH;
    const int w0 = blockIdx.x * TW;
    const int tid = threadIdx.x;

    // stage 8 channels with 1-px circular halo
    const int PER_CH = (TH + 2) * (TW + 2);       // 1188
    const int TOTAL  = C_ * PER_CH;               // 9504
    for (int i = tid; i < TOTAL; i += 256) {
        int c   = i / PER_CH;
        int rem = i - c * PER_CH;
        int r   = rem / (TW + 2);
        int col = rem - r * (TW + 2);
        int gh  = (h0 + r - 1) & (H_ - 1);
        int gw  = (w0 + col - 1) & (W_ - 1);
        (&lds[0][0][0])[i] = grid[(((b << 3) + c) << 18) + (gh << 9) + gw];
    }
    __syncthreads();

    const int lw  = tid & 63;          // 0..63 -> column in tile
    const int lh0 = (tid >> 6) << 2;   // 0,4,8,12 -> base row of 4-row strip

    float acc[C_][4];
    #pragma unroll
    for (int c = 0; c < C_; ++c)
        #pragma unroll
        for (int p = 0; p < 4; ++p) acc[c][p] = 0.f;

    for (int cp = 0; cp < C_; ++cp) {
        float v[6][3];
        #pragma unroll
        for (int r = 0; r < 6; ++r)
            #pragma unroll
            for (int cc = 0; cc < 3; ++cc)
                v[r][cc] = lds[cp][lh0 + r][lw + cc];

        #pragma unroll
        for (int c = 0; c < C_; ++c) {
            #pragma unroll
            for (int kh = 0; kh < 3; ++kh) {
                #pragma unroll
                for (int kw = 0; kw < 3; ++kw) {
                    const float kv = K[(c * C_ + cp) * 9 + kh * 3 + kw];
                    #pragma unroll
                    for (int p = 0; p < 4; ++p)
                        acc[c][p] += kv * v[p + kh][kw];
                }
            }
        }
    }

    // epilogue: mask, residual, clamp, store
    #pragma unroll
    for (int c = 0; c < C_; ++c) {
        #pragma unroll
        for (int p = 0; p < 4; ++p) {
            const int h  = h0 + lh0 + p;
            const int gi = (((b << 3) + c) << 18) + (h << 9) + (w0 + lw);
            const float g = lds[c][lh0 + p + 1][lw + 1];
            const float m = (noise[gi] < 0.5f) ? 1.0f : 0.0f;
            float nv = g + acc[c][p] * m;
            nv = fminf(fmaxf(nv, 0.0f), 1.0f);
            out[gi] = nv;
        }
    }
}

extern "C" void kernel_launch(void* const* d_in, const int* in_sizes, int n_in,
                              void* d_out, int out_size, void* d_ws, size_t ws_size,
                              hipStream_t stream)
{
    const float* grid    = (const float*)d_in[0];
    const float* noise   = (const float*)d_in[1];
    const float* filters = (const float*)d_in[2];
    const float* w0      = (const float*)d_in[3];
    const float* w1      = (const float*)d_in[4];
    float* out = (float*)d_out;
    float* K   = (float*)d_ws;   // 576 floats

    nca_prep<<<1, 576, 0, stream>>>(filters, w0, w1, K);

    dim3 g(W_ / TW, H_ / TH, B_);
    nca_main<<<g, 256, 0, stream>>>(grid, noise, K, out);
}